// Round 3
// baseline (685.574 us; speedup 1.0000x reference)
//
#include <hip/hip_runtime.h>
#include <math.h>

// weighted_loss: graph-weighted cross entropy.
//   deg/s0 per node (s1 = deg - s0), cnt = #nodes sharing key (x, s0, s1),
//   w = cnt^-0.5, out = sum(w*nll)/sum(w).
//
// Hard-won gfx950 facts driving this design:
//  R1-4: global atomics execute at the memory-side coherence point, ~26 G/s
//        distributed, 32 B write-through each, SCOPE-INDEPENDENT.
//  R7:   same-address global atomics serialize at ~12.5 ns/op.
//  R5-9: LDS-privatized counting + bucketed single-read pass: 740->256 us.
//  R10:  u16 bucket entries (local:15|xbit:1) halved pack writes/count reads.
//  R11:  49 parts regressed pack (store scatter worse).
//  R12:  NT stores: WRITE 25.7->74.7 MB, perf UNCHANGED -> pack is line-
//        TRANSACTION bound, not byte bound. ~3M scattered store-line touches
//        x ~900cyc poison-cold latency / ~64 MSHRs/CU ~= 63 us. FETCH 50MB is
//        the edge stream (102MB, half L3-absorbed), NOT bucket RMW.
//  R13 (this round): LDS software write-combining.
//        - hot loop: load edges -> LDS stage (atomic slot + u16 write); NO
//          global stores in the stream.
//        - per round (8192 edges/block): barrier, wave-per-partition flush of
//          consecutive runs -> fully coalesced 128B store instructions
//          (~16x fewer store-line transactions).
//        - host guards stage capacity (production: mean 671, cap 832);
//          pathological N -> fallback path.

#define KDIM 256
#define HIST_BINS (2 * KDIM * KDIM)
#define PART_BITS 14
#define PART_SIZE (1 << PART_BITS)       // 16384 nodes per partition
#define PART_WORDS (PART_SIZE / 2)       // 8192 u32, 2 nodes/word (s0:8|deg:8)
#define NPART_MAX 13
#define MAXN (NPART_MAX * PART_SIZE)     // 212992
#define BM_WORDS_MAX (MAXN / 32)         // 6656 u32 = 26.6 KB
#define PACK_BLOCKS 512
#define PACK_THREADS 1024
#define STAGE_TOTAL (NPART_MAX * 832)    // 10816 u16 entries = 21.6 KB
#define BPP 32                           // count replica blocks per partition
#define CSLICES (PACK_BLOCKS / BPP)      // 16 pack-segments per count block
#define COUNT_THREADS 512
#define LOSS_BLOCKS 256
#define OVF_CAP 65536

typedef int iv4 __attribute__((ext_vector_type(4)));
typedef unsigned int uv4 __attribute__((ext_vector_type(4)));

// ---------------- kernel A0: x -> bitmask (ballot) ----------------
__global__ __launch_bounds__(256) void bitmask_kernel(
    const int* __restrict__ x, unsigned int* __restrict__ bm, int N)
{
    int i = blockIdx.x * blockDim.x + threadIdx.x;
    unsigned long long m = __ballot(i < N && x[i] > 0);
    if ((i & 31) == 0 && i < N)
        bm[i >> 5] = (unsigned int)((i & 32) ? (m >> 32) : m);
}

// ---------------- kernel A: bucketing pack (LDS write-combined) ----------------
__global__ __launch_bounds__(PACK_THREADS, 8) void pack_bucket_kernel(
    const int* __restrict__ row, const int* __restrict__ col,
    const unsigned int* __restrict__ bm,
    unsigned short* __restrict__ buckets,
    int* __restrict__ gSegCnt,           // [PACK_BLOCKS][NPART_MAX]
    unsigned int* __restrict__ ovf, unsigned int* __restrict__ ovfCnt,
    int cap, int npart, int bmWords, int E)
{
    __shared__ unsigned int bmLds[BM_WORDS_MAX];        // 26.6 KB
    __shared__ unsigned short stage[STAGE_TOTAL];       // 21.6 KB
    __shared__ int stageCnt[NPART_MAX];
    __shared__ int offLds[NPART_MAX];
    for (int w = threadIdx.x; w < bmWords; w += blockDim.x) bmLds[w] = bm[w];
    if (threadIdx.x < NPART_MAX) { stageCnt[threadIdx.x] = 0; offLds[threadIdx.x] = 0; }
    __syncthreads();

    int tid = blockIdx.x * blockDim.x + threadIdx.x;
    int stride = gridDim.x * blockDim.x;
    int E4 = E >> 2;
    const iv4* row4 = (const iv4*)row;
    const iv4* col4 = (const iv4*)col;
    int stageCap = STAGE_TOTAL / npart;
    int wave = threadIdx.x >> 6;
    int lane = threadIdx.x & 63;
    int nwaves = blockDim.x >> 6;
    int nrounds = (E4 + 2 * stride - 1) / (2 * stride);
    if (nrounds < 1) nrounds = 1;

#define XBIT(c) ((bmLds[((unsigned)(c)) >> 5] >> ((c) & 31)) & 1u)
#define PUT(nd, cl)                                                             \
    {                                                                           \
        unsigned int node = (unsigned int)(nd);                                 \
        unsigned int xb = XBIT(cl);                                             \
        int b = (int)(node >> PART_BITS);                                       \
        unsigned int entry = ((node & (PART_SIZE - 1u)) << 1) | xb;             \
        int slot = atomicAdd(&stageCnt[b], 1);                                  \
        if (slot < stageCap)                                                    \
            stage[b * stageCap + slot] = (unsigned short)entry;                 \
        else {                                                                  \
            unsigned int os = atomicAdd(ovfCnt, 1u);                            \
            if (os < OVF_CAP) ovf[os] = (node << 1) | xb;                       \
        }                                                                       \
    }

    for (int r = 0; r < nrounds; ++r) {
        int i = tid + r * 2 * stride;
        if (i + stride < E4) {
            iv4 r0 = __builtin_nontemporal_load(&row4[i]);
            iv4 c0 = __builtin_nontemporal_load(&col4[i]);
            iv4 r1 = __builtin_nontemporal_load(&row4[i + stride]);
            iv4 c1 = __builtin_nontemporal_load(&col4[i + stride]);
            PUT(r0.x, c0.x) PUT(r0.y, c0.y) PUT(r0.z, c0.z) PUT(r0.w, c0.w)
            PUT(r1.x, c1.x) PUT(r1.y, c1.y) PUT(r1.z, c1.z) PUT(r1.w, c1.w)
        } else if (i < E4) {
            iv4 r0 = __builtin_nontemporal_load(&row4[i]);
            iv4 c0 = __builtin_nontemporal_load(&col4[i]);
            PUT(r0.x, c0.x) PUT(r0.y, c0.y) PUT(r0.z, c0.z) PUT(r0.w, c0.w)
        }
        if (r == nrounds - 1) {
            for (int e = (E4 << 2) + tid; e < E; e += stride)
                PUT(row[e], col[e])
        }
        __syncthreads();
        // flush: one wave per partition, consecutive (coalesced) stores
        for (int b = wave; b < npart; b += nwaves) {
            int cnt = stageCnt[b];
            if (cnt > stageCap) cnt = stageCap;
            int off = offLds[b];
            int avail = cap - off;
            if (avail < 0) avail = 0;
            int wr = cnt < avail ? cnt : avail;
            unsigned short* dst =
                buckets + (size_t)(b * PACK_BLOCKS + (int)blockIdx.x) * (size_t)cap + off;
            const unsigned short* src = stage + b * stageCap;
            for (int k = lane; k < wr; k += 64) dst[k] = src[k];
            for (int k = wr + lane; k < cnt; k += 64) {   // beyond cap: spill
                unsigned int en = src[k];
                unsigned int node = ((unsigned int)b << PART_BITS) | (en >> 1);
                unsigned int os = atomicAdd(ovfCnt, 1u);
                if (os < OVF_CAP) ovf[os] = (node << 1) | (en & 1u);
            }
            if (lane == 0) { offLds[b] = off + wr; stageCnt[b] = 0; }
        }
        __syncthreads();
    }
#undef PUT
#undef XBIT

    if (threadIdx.x < npart)
        gSegCnt[blockIdx.x * NPART_MAX + threadIdx.x] = offLds[threadIdx.x];
}

// ---------------- kernel B: single-read LDS-privatized count ----------------
// One block = (partition p, replica grp). Each WAVE owns whole pack-segments
// (cnt ~2048 -> cnt8 ~256 -> all 64 lanes active, 4 uv4 iters per segment).
__global__ __launch_bounds__(COUNT_THREADS, 8) void count_bucket_kernel(
    const unsigned short* __restrict__ buckets, const int* __restrict__ gSegCnt,
    const unsigned int* __restrict__ ovf, const unsigned int* __restrict__ ovfCnt,
    int cap, unsigned int* __restrict__ scratch)
{
    __shared__ unsigned int lds[PART_WORDS];   // 32 KB
    int p = blockIdx.x / BPP;
    int grp = blockIdx.x % BPP;
    for (int w = threadIdx.x; w < PART_WORDS; w += blockDim.x) lds[w] = 0;
    __syncthreads();

#define DO1(e)                                                                  \
    {                                                                           \
        unsigned int j = (e) >> 1;  /* partition-local: always < PART_SIZE */   \
        unsigned int val = (((e) & 1u) ? 0x0101u : 0x0001u) << ((j & 1u) << 4); \
        atomicAdd(&lds[j >> 1], val);                                           \
    }
#define DOW(w) { DO1((w) & 0xFFFFu) DO1((w) >> 16) }
    int sl0 = grp * CSLICES;
    int wave = threadIdx.x >> 6;
    int lane = threadIdx.x & 63;
    int nw = COUNT_THREADS >> 6;   // 8 waves
    for (int s = wave; s < CSLICES; s += nw) {
        int pb = sl0 + s;
        int cnt = gSegCnt[pb * NPART_MAX + p];
        const unsigned short* base =
            buckets + (size_t)(p * PACK_BLOCKS + pb) * (size_t)cap;
        // 16B-aligned (cap %8==0): read 8 entries per uv4
        const uv4* b8 = (const uv4*)base;
        int cnt8 = cnt >> 3;
        for (int i = lane; i < cnt8; i += 64) {
            uv4 v = b8[i];
            DOW(v.x) DOW(v.y) DOW(v.z) DOW(v.w)
        }
        for (int k = (cnt8 << 3) + lane; k < cnt; k += 64)
            DO1((unsigned int)base[k]);
    }
    // overflow region (normally empty): full node<<1|xbit u32 entries,
    // filtered by partition; grp 0 only (others would double-count).
    if (grp == 0) {
        unsigned int oc = *ovfCnt;
        if (oc > OVF_CAP) oc = OVF_CAP;
        unsigned int pbase = (unsigned int)p << PART_BITS;
        for (unsigned int i = threadIdx.x; i < oc; i += blockDim.x) {
            unsigned int e = ovf[i];
            unsigned int j = (e >> 1) - pbase;
            if (j < PART_SIZE) {
                unsigned int val = ((e & 1u) ? 0x0101u : 0x0001u) << ((j & 1u) << 4);
                atomicAdd(&lds[j >> 1], val);
            }
        }
    }
#undef DOW
#undef DO1
    __syncthreads();
    unsigned int* dst = scratch + (size_t)blockIdx.x * PART_WORDS;
    for (int w = threadIdx.x; w < PART_WORDS; w += blockDim.x)
        dst[w] = lds[w];
}

// ---------------- kernel C: merge replicas + key histogram ----------------
__global__ __launch_bounds__(256) void merge_hist_kernel(
    const unsigned int* __restrict__ scratch, const int* __restrict__ x,
    unsigned int* __restrict__ p_m, int* __restrict__ hist, int N, int npart)
{
    int gw = blockIdx.x * blockDim.x + threadIdx.x;
    if (gw >= npart * PART_WORDS) return;
    int part = gw >> (PART_BITS - 1);
    int lw = gw & (PART_WORDS - 1);
    const unsigned int* base = scratch + ((size_t)part * BPP) * PART_WORDS + lw;
    unsigned int s = 0;
#pragma unroll 8
    for (int c = 0; c < BPP; ++c) s += base[(size_t)c * PART_WORDS];
    // byte fields sum without carry: true deg <= ~110 < 256
    int node0 = (part << PART_BITS) | (lw << 1);
    if (node0 < N) {
        unsigned int deg = s & 0xFFu, s0 = (s >> 8) & 0xFFu;
        p_m[node0] = deg | (s0 << 16);
        int key = ((x[node0] > 0) ? KDIM * KDIM : 0) + (int)(s0 * KDIM + (deg - s0));
        atomicAdd(&hist[key], 1);
    }
    int node1 = node0 + 1;
    if (node1 < N) {
        unsigned int deg = (s >> 16) & 0xFFu, s0 = (s >> 24) & 0xFFu;
        p_m[node1] = deg | (s0 << 16);
        int key = ((x[node1] > 0) ? KDIM * KDIM : 0) + (int)(s0 * KDIM + (deg - s0));
        atomicAdd(&hist[key], 1);
    }
}

// ---------------- fallback path (ws too small / N too big) ----------------
__global__ __launch_bounds__(256) void edge_atomic_kernel(
    const int* __restrict__ row, const int* __restrict__ col,
    const int* __restrict__ x, unsigned int* __restrict__ p_m, int E)
{
    int tid = blockIdx.x * blockDim.x + threadIdx.x;
    int stride = gridDim.x * blockDim.x;
    int E4 = E >> 2;
    const iv4* row4 = (const iv4*)row;
    const iv4* col4 = (const iv4*)col;
    for (int i = tid; i < E4; i += stride) {
        iv4 r = row4[i];
        iv4 c = col4[i];
        atomicAdd(&p_m[r.x], (x[c.x] > 0) ? 0x10001u : 1u);
        atomicAdd(&p_m[r.y], (x[c.y] > 0) ? 0x10001u : 1u);
        atomicAdd(&p_m[r.z], (x[c.z] > 0) ? 0x10001u : 1u);
        atomicAdd(&p_m[r.w], (x[c.w] > 0) ? 0x10001u : 1u);
    }
    for (int e = (E4 << 2) + tid; e < E; e += stride)
        atomicAdd(&p_m[row[e]], (x[col[e]] > 0) ? 0x10001u : 1u);
}

__global__ void hist_from_pm_kernel(const int* __restrict__ x,
                                    const unsigned int* __restrict__ p_m,
                                    int* __restrict__ hist, int N)
{
    int i = blockIdx.x * blockDim.x + threadIdx.x;
    if (i >= N) return;
    unsigned int pi = p_m[i];
    int deg = (int)(pi & 0xFFFFu);
    int s0 = (int)(pi >> 16);
    int s1 = deg - s0;
    s0 = min(s0, KDIM - 1);
    s1 = min(s1, KDIM - 1);
    int key = ((x[i] > 0) ? KDIM * KDIM : 0) + s0 * KDIM + s1;
    atomicAdd(&hist[key], 1);
}

// ---------------- kernel D: weighted NLL -> per-block partials ----------------
__global__ __launch_bounds__(256) void loss_kernel(
    const float* __restrict__ outp, const int* __restrict__ x,
    const int* __restrict__ y, const unsigned int* __restrict__ p_m,
    const int* __restrict__ hist, double* __restrict__ partials, int N)
{
    __shared__ double red[8];
    int tid = blockIdx.x * blockDim.x + threadIdx.x;
    int stride = gridDim.x * blockDim.x;
    double wn = 0.0, wsum = 0.0;
    const float2* out2 = (const float2*)outp;
    for (int i = tid; i < N; i += stride) {
        unsigned int pi = p_m[i];
        int deg = (int)(pi & 0xFFFFu);
        int s0 = (int)(pi >> 16);
        int s1 = deg - s0;
        s0 = min(s0, KDIM - 1);
        s1 = min(s1, KDIM - 1);
        int key = ((x[i] > 0) ? KDIM * KDIM : 0) + s0 * KDIM + s1;
        int cnt = hist[key];
        float w = 1.0f / sqrtf((float)cnt);
        float2 o = out2[i];
        float m = fmaxf(o.x, o.y);
        float lse = m + logf(expf(o.x - m) + expf(o.y - m));
        float oy = (y[i] == 0) ? o.x : o.y;
        wn += (double)(w * (lse - oy));
        wsum += (double)w;
    }
    for (int off = 32; off > 0; off >>= 1) {
        wn += __shfl_down(wn, off);
        wsum += __shfl_down(wsum, off);
    }
    int wave = threadIdx.x >> 6;
    if ((threadIdx.x & 63) == 0) { red[wave * 2] = wn; red[wave * 2 + 1] = wsum; }
    __syncthreads();
    if (threadIdx.x == 0) {
        double twn = 0.0, tws = 0.0;
        for (int wv = 0; wv < (int)(blockDim.x >> 6); ++wv) {
            twn += red[wv * 2]; tws += red[wv * 2 + 1];
        }
        partials[blockIdx.x * 2] = twn;
        partials[blockIdx.x * 2 + 1] = tws;
    }
}

__global__ __launch_bounds__(256) void final_kernel(
    const double* __restrict__ partials, float* __restrict__ out, int nPart)
{
    __shared__ double red[8];
    double wn = 0.0, wsum = 0.0;
    for (int i = threadIdx.x; i < nPart; i += blockDim.x) {
        wn += partials[i * 2];
        wsum += partials[i * 2 + 1];
    }
    for (int off = 32; off > 0; off >>= 1) {
        wn += __shfl_down(wn, off);
        wsum += __shfl_down(wsum, off);
    }
    int wave = threadIdx.x >> 6;
    if ((threadIdx.x & 63) == 0) { red[wave * 2] = wn; red[wave * 2 + 1] = wsum; }
    __syncthreads();
    if (threadIdx.x == 0) {
        double twn = 0.0, tws = 0.0;
        for (int wv = 0; wv < (int)(blockDim.x >> 6); ++wv) {
            twn += red[wv * 2]; tws += red[wv * 2 + 1];
        }
        out[0] = (float)(twn / tws);
    }
}

extern "C" void kernel_launch(void* const* d_in, const int* in_sizes, int n_in,
                              void* d_out, int out_size, void* d_ws, size_t ws_size,
                              hipStream_t stream) {
    const float* outp = (const float*)d_in[0];   // (N,2) fp32
    const int*   x    = (const int*)d_in[1];     // (N,)
    const int*   y    = (const int*)d_in[2];     // (N,)
    const int*   ei   = (const int*)d_in[3];     // (2,E)
    int N = in_sizes[1];
    int E = in_sizes[3] / 2;
    const int* row = ei;
    const int* col = ei + E;

    // uniform per-(block,partition) capacity: mean + 8 sigma + 64, %8==0
    int npart = (N > 0) ? (N + PART_SIZE - 1) / PART_SIZE : 1;
    double mb = (N > 0) ? (double)E * PART_SIZE / N / PACK_BLOCKS : 0.0;
    int cap = ((int)(mb + 8.0 * sqrt(mb + 1.0) + 64.0) + 7) & ~7;
    size_t bucketShorts = (size_t)npart * PACK_BLOCKS * (size_t)cap;
    int nblkCount = npart * BPP;

    // LDS stage-capacity guard: per round a block stages 8192 edges; the
    // hottest partition must fit in STAGE_TOTAL/npart with 8-sigma margin.
    int stageCap = STAGE_TOTAL / npart;
    double mbR = 8192.0 * ((N >= PART_SIZE) ? ((double)PART_SIZE / (double)N) : 1.0);
    bool stageOk = (N > 0) && (mbR + 8.0 * sqrt(mbR + 1.0) + 32.0) <= (double)stageCap;

    // ws layout: [partials 4K][hist 512K][ovfCnt 256B][gSegCnt]
    //            [p_m][ovf 256K][bm 26.6K][buckets u16][scratch]
    char* ws = (char*)d_ws;
    double* partials = (double*)ws;
    size_t histOff = 4096;
    int* hist = (int*)(ws + histOff);
    size_t ovfCntOff = histOff + (size_t)HIST_BINS * sizeof(int);
    unsigned int* ovfCnt = (unsigned int*)(ws + ovfCntOff);
    size_t gSegOff = ovfCntOff + 256;
    int* gSegCnt = (int*)(ws + gSegOff);
    size_t pmOff = gSegOff + (((size_t)PACK_BLOCKS * NPART_MAX * sizeof(int) + 255) & ~(size_t)255);
    unsigned int* p_m = (unsigned int*)(ws + pmOff);
    size_t pmBytes = ((size_t)N * 4 + 255) & ~(size_t)255;
    size_t ovfOff = pmOff + pmBytes;
    unsigned int* ovf = (unsigned int*)(ws + ovfOff);
    size_t bmOff = ovfOff + (size_t)OVF_CAP * 4;
    unsigned int* bm = (unsigned int*)(ws + bmOff);
    size_t bucketsOff = bmOff + (size_t)BM_WORDS_MAX * 4;
    unsigned short* buckets = (unsigned short*)(ws + bucketsOff);
    size_t scratchOff = bucketsOff + ((bucketShorts * 2 + 255) & ~(size_t)255);
    unsigned int* scratch = (unsigned int*)(ws + scratchOff);
    size_t totalFast = scratchOff + (size_t)nblkCount * PART_WORDS * 4;

    bool fast = (ws_size >= totalFast) && (N <= MAXN) && (N > 0) && stageOk;
    const int threads = 256;
    int nblocks = (N + threads - 1) / threads;
    int bmWords = (N + 31) / 32;

    if (fast) {
        // zero hist + ovfCnt (contiguous); everything else is fully written
        (void)hipMemsetAsync(ws + histOff, 0, (size_t)HIST_BINS * sizeof(int) + 256, stream);
        bitmask_kernel<<<nblocks, threads, 0, stream>>>(x, bm, N);
        pack_bucket_kernel<<<PACK_BLOCKS, PACK_THREADS, 0, stream>>>(
            row, col, bm, buckets, gSegCnt, ovf, ovfCnt, cap, npart, bmWords, E);
        count_bucket_kernel<<<nblkCount, COUNT_THREADS, 0, stream>>>(
            buckets, gSegCnt, ovf, ovfCnt, cap, scratch);
        int mwords = npart * PART_WORDS;
        int mblocks = (mwords + threads - 1) / threads;
        merge_hist_kernel<<<mblocks, threads, 0, stream>>>(scratch, x, p_m, hist, N, npart);
    } else {
        (void)hipMemsetAsync(d_ws, 0, pmOff + pmBytes, stream);
        int E4 = E >> 2;
        int eblocks = (E4 + threads - 1) / threads;
        if (eblocks < 1) eblocks = 1;
        edge_atomic_kernel<<<eblocks, threads, 0, stream>>>(row, col, x, p_m, E);
        hist_from_pm_kernel<<<nblocks, threads, 0, stream>>>(x, p_m, hist, N);
    }
    loss_kernel<<<LOSS_BLOCKS, threads, 0, stream>>>(outp, x, y, p_m, hist, partials, N);
    final_kernel<<<1, threads, 0, stream>>>(partials, (float*)d_out, LOSS_BLOCKS);
}

// Round 4
// 228.819 us; speedup vs baseline: 2.9961x; 2.9961x over previous
//
#include <hip/hip_runtime.h>
#include <math.h>

// weighted_loss: graph-weighted cross entropy.
//   deg/s0 per node (s1 = deg - s0), cnt = #nodes sharing key (x, s0, s1),
//   w = cnt^-0.5, out = sum(w*nll)/sum(w).
//
// Hard-won gfx950 facts driving this design:
//  R1-4: global atomics execute at the memory-side coherence point, ~26 G/s
//        distributed, 32 B write-through each, SCOPE-INDEPENDENT.
//  R7:   same-address global atomics serialize at ~12.5 ns/op.
//  R5-9: LDS-privatized counting + bucketed single-read pass: 740->256 us.
//  R10:  u16 bucket entries (local:15|xbit:1) halved pack writes/count reads.
//  R11:  49 parts regressed pack (store scatter worse).
//  R12:  NT stores: WRITE 25.7->74.7 MB, perf UNCHANGED -> pack is line-
//        TRANSACTION bound, not byte bound. ~3M scattered store-line touches
//        x ~900cyc poison-cold latency / ~64 MSHRs/CU ~= 63 us. FETCH 50MB is
//        the edge stream (102MB, half L3-absorbed), NOT bucket RMW.
//  R13:  LDS write-combining pack — but stage guard (cap 832 < need 910)
//        silently sent production to the FALLBACK (685us). Theory untested.
//  R14 (this round): stage = 1024 entries/partition (26.6KB; total LDS
//        53.3KB, still 2 blocks/CU) -> guard passes at production with
//        ~14-sigma spill headroom. Hot loop: coalesced loads -> LDS stage;
//        per-round wave-per-partition flush = consecutive 128B stores.

#define KDIM 256
#define HIST_BINS (2 * KDIM * KDIM)
#define PART_BITS 14
#define PART_SIZE (1 << PART_BITS)       // 16384 nodes per partition
#define PART_WORDS (PART_SIZE / 2)       // 8192 u32, 2 nodes/word (s0:8|deg:8)
#define NPART_MAX 13
#define MAXN (NPART_MAX * PART_SIZE)     // 212992
#define BM_WORDS_MAX (MAXN / 32)         // 6656 u32 = 26.6 KB
#define PACK_BLOCKS 512
#define PACK_THREADS 1024
#define STAGE_TOTAL (NPART_MAX * 1024)   // 13312 u16 entries = 26.6 KB
#define BPP 32                           // count replica blocks per partition
#define CSLICES (PACK_BLOCKS / BPP)      // 16 pack-segments per count block
#define COUNT_THREADS 512
#define LOSS_BLOCKS 256
#define OVF_CAP 65536

typedef int iv4 __attribute__((ext_vector_type(4)));
typedef unsigned int uv4 __attribute__((ext_vector_type(4)));

// ---------------- kernel A0: x -> bitmask (ballot) ----------------
__global__ __launch_bounds__(256) void bitmask_kernel(
    const int* __restrict__ x, unsigned int* __restrict__ bm, int N)
{
    int i = blockIdx.x * blockDim.x + threadIdx.x;
    unsigned long long m = __ballot(i < N && x[i] > 0);
    if ((i & 31) == 0 && i < N)
        bm[i >> 5] = (unsigned int)((i & 32) ? (m >> 32) : m);
}

// ---------------- kernel A: bucketing pack (LDS write-combined) ----------------
__global__ __launch_bounds__(PACK_THREADS, 8) void pack_bucket_kernel(
    const int* __restrict__ row, const int* __restrict__ col,
    const unsigned int* __restrict__ bm,
    unsigned short* __restrict__ buckets,
    int* __restrict__ gSegCnt,           // [PACK_BLOCKS][NPART_MAX]
    unsigned int* __restrict__ ovf, unsigned int* __restrict__ ovfCnt,
    int cap, int npart, int bmWords, int E)
{
    __shared__ unsigned int bmLds[BM_WORDS_MAX];        // 26.6 KB
    __shared__ unsigned short stage[STAGE_TOTAL];       // 26.6 KB
    __shared__ int stageCnt[NPART_MAX];
    __shared__ int offLds[NPART_MAX];
    for (int w = threadIdx.x; w < bmWords; w += blockDim.x) bmLds[w] = bm[w];
    if (threadIdx.x < NPART_MAX) { stageCnt[threadIdx.x] = 0; offLds[threadIdx.x] = 0; }
    __syncthreads();

    int tid = blockIdx.x * blockDim.x + threadIdx.x;
    int stride = gridDim.x * blockDim.x;
    int E4 = E >> 2;
    const iv4* row4 = (const iv4*)row;
    const iv4* col4 = (const iv4*)col;
    int stageCap = STAGE_TOTAL / npart;
    int wave = threadIdx.x >> 6;
    int lane = threadIdx.x & 63;
    int nwaves = blockDim.x >> 6;
    int nrounds = (E4 + 2 * stride - 1) / (2 * stride);
    if (nrounds < 1) nrounds = 1;

#define XBIT(c) ((bmLds[((unsigned)(c)) >> 5] >> ((c) & 31)) & 1u)
#define PUT(nd, cl)                                                             \
    {                                                                           \
        unsigned int node = (unsigned int)(nd);                                 \
        unsigned int xb = XBIT(cl);                                             \
        int b = (int)(node >> PART_BITS);                                       \
        unsigned int entry = ((node & (PART_SIZE - 1u)) << 1) | xb;             \
        int slot = atomicAdd(&stageCnt[b], 1);                                  \
        if (slot < stageCap)                                                    \
            stage[b * stageCap + slot] = (unsigned short)entry;                 \
        else {                                                                  \
            unsigned int os = atomicAdd(ovfCnt, 1u);                            \
            if (os < OVF_CAP) ovf[os] = (node << 1) | xb;                       \
        }                                                                       \
    }

    for (int r = 0; r < nrounds; ++r) {
        int i = tid + r * 2 * stride;
        if (i + stride < E4) {
            iv4 r0 = __builtin_nontemporal_load(&row4[i]);
            iv4 c0 = __builtin_nontemporal_load(&col4[i]);
            iv4 r1 = __builtin_nontemporal_load(&row4[i + stride]);
            iv4 c1 = __builtin_nontemporal_load(&col4[i + stride]);
            PUT(r0.x, c0.x) PUT(r0.y, c0.y) PUT(r0.z, c0.z) PUT(r0.w, c0.w)
            PUT(r1.x, c1.x) PUT(r1.y, c1.y) PUT(r1.z, c1.z) PUT(r1.w, c1.w)
        } else if (i < E4) {
            iv4 r0 = __builtin_nontemporal_load(&row4[i]);
            iv4 c0 = __builtin_nontemporal_load(&col4[i]);
            PUT(r0.x, c0.x) PUT(r0.y, c0.y) PUT(r0.z, c0.z) PUT(r0.w, c0.w)
        }
        if (r == nrounds - 1) {
            for (int e = (E4 << 2) + tid; e < E; e += stride)
                PUT(row[e], col[e])
        }
        __syncthreads();
        // flush: one wave per partition, consecutive (coalesced) stores
        for (int b = wave; b < npart; b += nwaves) {
            int cnt = stageCnt[b];
            if (cnt > stageCap) cnt = stageCap;
            int off = offLds[b];
            int avail = cap - off;
            if (avail < 0) avail = 0;
            int wr = cnt < avail ? cnt : avail;
            unsigned short* dst =
                buckets + (size_t)(b * PACK_BLOCKS + (int)blockIdx.x) * (size_t)cap + off;
            const unsigned short* src = stage + b * stageCap;
            for (int k = lane; k < wr; k += 64) dst[k] = src[k];
            for (int k = wr + lane; k < cnt; k += 64) {   // beyond cap: spill
                unsigned int en = src[k];
                unsigned int node = ((unsigned int)b << PART_BITS) | (en >> 1);
                unsigned int os = atomicAdd(ovfCnt, 1u);
                if (os < OVF_CAP) ovf[os] = (node << 1) | (en & 1u);
            }
            if (lane == 0) { offLds[b] = off + wr; stageCnt[b] = 0; }
        }
        __syncthreads();
    }
#undef PUT
#undef XBIT

    if (threadIdx.x < npart)
        gSegCnt[blockIdx.x * NPART_MAX + threadIdx.x] = offLds[threadIdx.x];
}

// ---------------- kernel B: single-read LDS-privatized count ----------------
// One block = (partition p, replica grp). Each WAVE owns whole pack-segments
// (cnt ~2048 -> cnt8 ~256 -> all 64 lanes active, 4 uv4 iters per segment).
__global__ __launch_bounds__(COUNT_THREADS, 8) void count_bucket_kernel(
    const unsigned short* __restrict__ buckets, const int* __restrict__ gSegCnt,
    const unsigned int* __restrict__ ovf, const unsigned int* __restrict__ ovfCnt,
    int cap, unsigned int* __restrict__ scratch)
{
    __shared__ unsigned int lds[PART_WORDS];   // 32 KB
    int p = blockIdx.x / BPP;
    int grp = blockIdx.x % BPP;
    for (int w = threadIdx.x; w < PART_WORDS; w += blockDim.x) lds[w] = 0;
    __syncthreads();

#define DO1(e)                                                                  \
    {                                                                           \
        unsigned int j = (e) >> 1;  /* partition-local: always < PART_SIZE */   \
        unsigned int val = (((e) & 1u) ? 0x0101u : 0x0001u) << ((j & 1u) << 4); \
        atomicAdd(&lds[j >> 1], val);                                           \
    }
#define DOW(w) { DO1((w) & 0xFFFFu) DO1((w) >> 16) }
    int sl0 = grp * CSLICES;
    int wave = threadIdx.x >> 6;
    int lane = threadIdx.x & 63;
    int nw = COUNT_THREADS >> 6;   // 8 waves
    for (int s = wave; s < CSLICES; s += nw) {
        int pb = sl0 + s;
        int cnt = gSegCnt[pb * NPART_MAX + p];
        const unsigned short* base =
            buckets + (size_t)(p * PACK_BLOCKS + pb) * (size_t)cap;
        // 16B-aligned (cap %8==0): read 8 entries per uv4
        const uv4* b8 = (const uv4*)base;
        int cnt8 = cnt >> 3;
        for (int i = lane; i < cnt8; i += 64) {
            uv4 v = b8[i];
            DOW(v.x) DOW(v.y) DOW(v.z) DOW(v.w)
        }
        for (int k = (cnt8 << 3) + lane; k < cnt; k += 64)
            DO1((unsigned int)base[k]);
    }
    // overflow region (normally empty): full node<<1|xbit u32 entries,
    // filtered by partition; grp 0 only (others would double-count).
    if (grp == 0) {
        unsigned int oc = *ovfCnt;
        if (oc > OVF_CAP) oc = OVF_CAP;
        unsigned int pbase = (unsigned int)p << PART_BITS;
        for (unsigned int i = threadIdx.x; i < oc; i += blockDim.x) {
            unsigned int e = ovf[i];
            unsigned int j = (e >> 1) - pbase;
            if (j < PART_SIZE) {
                unsigned int val = ((e & 1u) ? 0x0101u : 0x0001u) << ((j & 1u) << 4);
                atomicAdd(&lds[j >> 1], val);
            }
        }
    }
#undef DOW
#undef DO1
    __syncthreads();
    unsigned int* dst = scratch + (size_t)blockIdx.x * PART_WORDS;
    for (int w = threadIdx.x; w < PART_WORDS; w += blockDim.x)
        dst[w] = lds[w];
}

// ---------------- kernel C: merge replicas + key histogram ----------------
__global__ __launch_bounds__(256) void merge_hist_kernel(
    const unsigned int* __restrict__ scratch, const int* __restrict__ x,
    unsigned int* __restrict__ p_m, int* __restrict__ hist, int N, int npart)
{
    int gw = blockIdx.x * blockDim.x + threadIdx.x;
    if (gw >= npart * PART_WORDS) return;
    int part = gw >> (PART_BITS - 1);
    int lw = gw & (PART_WORDS - 1);
    const unsigned int* base = scratch + ((size_t)part * BPP) * PART_WORDS + lw;
    unsigned int s = 0;
#pragma unroll 8
    for (int c = 0; c < BPP; ++c) s += base[(size_t)c * PART_WORDS];
    // byte fields sum without carry: true deg <= ~110 < 256
    int node0 = (part << PART_BITS) | (lw << 1);
    if (node0 < N) {
        unsigned int deg = s & 0xFFu, s0 = (s >> 8) & 0xFFu;
        p_m[node0] = deg | (s0 << 16);
        int key = ((x[node0] > 0) ? KDIM * KDIM : 0) + (int)(s0 * KDIM + (deg - s0));
        atomicAdd(&hist[key], 1);
    }
    int node1 = node0 + 1;
    if (node1 < N) {
        unsigned int deg = (s >> 16) & 0xFFu, s0 = (s >> 24) & 0xFFu;
        p_m[node1] = deg | (s0 << 16);
        int key = ((x[node1] > 0) ? KDIM * KDIM : 0) + (int)(s0 * KDIM + (deg - s0));
        atomicAdd(&hist[key], 1);
    }
}

// ---------------- fallback path (ws too small / N too big) ----------------
__global__ __launch_bounds__(256) void edge_atomic_kernel(
    const int* __restrict__ row, const int* __restrict__ col,
    const int* __restrict__ x, unsigned int* __restrict__ p_m, int E)
{
    int tid = blockIdx.x * blockDim.x + threadIdx.x;
    int stride = gridDim.x * blockDim.x;
    int E4 = E >> 2;
    const iv4* row4 = (const iv4*)row;
    const iv4* col4 = (const iv4*)col;
    for (int i = tid; i < E4; i += stride) {
        iv4 r = row4[i];
        iv4 c = col4[i];
        atomicAdd(&p_m[r.x], (x[c.x] > 0) ? 0x10001u : 1u);
        atomicAdd(&p_m[r.y], (x[c.y] > 0) ? 0x10001u : 1u);
        atomicAdd(&p_m[r.z], (x[c.z] > 0) ? 0x10001u : 1u);
        atomicAdd(&p_m[r.w], (x[c.w] > 0) ? 0x10001u : 1u);
    }
    for (int e = (E4 << 2) + tid; e < E; e += stride)
        atomicAdd(&p_m[row[e]], (x[col[e]] > 0) ? 0x10001u : 1u);
}

__global__ void hist_from_pm_kernel(const int* __restrict__ x,
                                    const unsigned int* __restrict__ p_m,
                                    int* __restrict__ hist, int N)
{
    int i = blockIdx.x * blockDim.x + threadIdx.x;
    if (i >= N) return;
    unsigned int pi = p_m[i];
    int deg = (int)(pi & 0xFFFFu);
    int s0 = (int)(pi >> 16);
    int s1 = deg - s0;
    s0 = min(s0, KDIM - 1);
    s1 = min(s1, KDIM - 1);
    int key = ((x[i] > 0) ? KDIM * KDIM : 0) + s0 * KDIM + s1;
    atomicAdd(&hist[key], 1);
}

// ---------------- kernel D: weighted NLL -> per-block partials ----------------
__global__ __launch_bounds__(256) void loss_kernel(
    const float* __restrict__ outp, const int* __restrict__ x,
    const int* __restrict__ y, const unsigned int* __restrict__ p_m,
    const int* __restrict__ hist, double* __restrict__ partials, int N)
{
    __shared__ double red[8];
    int tid = blockIdx.x * blockDim.x + threadIdx.x;
    int stride = gridDim.x * blockDim.x;
    double wn = 0.0, wsum = 0.0;
    const float2* out2 = (const float2*)outp;
    for (int i = tid; i < N; i += stride) {
        unsigned int pi = p_m[i];
        int deg = (int)(pi & 0xFFFFu);
        int s0 = (int)(pi >> 16);
        int s1 = deg - s0;
        s0 = min(s0, KDIM - 1);
        s1 = min(s1, KDIM - 1);
        int key = ((x[i] > 0) ? KDIM * KDIM : 0) + s0 * KDIM + s1;
        int cnt = hist[key];
        float w = 1.0f / sqrtf((float)cnt);
        float2 o = out2[i];
        float m = fmaxf(o.x, o.y);
        float lse = m + logf(expf(o.x - m) + expf(o.y - m));
        float oy = (y[i] == 0) ? o.x : o.y;
        wn += (double)(w * (lse - oy));
        wsum += (double)w;
    }
    for (int off = 32; off > 0; off >>= 1) {
        wn += __shfl_down(wn, off);
        wsum += __shfl_down(wsum, off);
    }
    int wave = threadIdx.x >> 6;
    if ((threadIdx.x & 63) == 0) { red[wave * 2] = wn; red[wave * 2 + 1] = wsum; }
    __syncthreads();
    if (threadIdx.x == 0) {
        double twn = 0.0, tws = 0.0;
        for (int wv = 0; wv < (int)(blockDim.x >> 6); ++wv) {
            twn += red[wv * 2]; tws += red[wv * 2 + 1];
        }
        partials[blockIdx.x * 2] = twn;
        partials[blockIdx.x * 2 + 1] = tws;
    }
}

__global__ __launch_bounds__(256) void final_kernel(
    const double* __restrict__ partials, float* __restrict__ out, int nPart)
{
    __shared__ double red[8];
    double wn = 0.0, wsum = 0.0;
    for (int i = threadIdx.x; i < nPart; i += blockDim.x) {
        wn += partials[i * 2];
        wsum += partials[i * 2 + 1];
    }
    for (int off = 32; off > 0; off >>= 1) {
        wn += __shfl_down(wn, off);
        wsum += __shfl_down(wsum, off);
    }
    int wave = threadIdx.x >> 6;
    if ((threadIdx.x & 63) == 0) { red[wave * 2] = wn; red[wave * 2 + 1] = wsum; }
    __syncthreads();
    if (threadIdx.x == 0) {
        double twn = 0.0, tws = 0.0;
        for (int wv = 0; wv < (int)(blockDim.x >> 6); ++wv) {
            twn += red[wv * 2]; tws += red[wv * 2 + 1];
        }
        out[0] = (float)(twn / tws);
    }
}

extern "C" void kernel_launch(void* const* d_in, const int* in_sizes, int n_in,
                              void* d_out, int out_size, void* d_ws, size_t ws_size,
                              hipStream_t stream) {
    const float* outp = (const float*)d_in[0];   // (N,2) fp32
    const int*   x    = (const int*)d_in[1];     // (N,)
    const int*   y    = (const int*)d_in[2];     // (N,)
    const int*   ei   = (const int*)d_in[3];     // (2,E)
    int N = in_sizes[1];
    int E = in_sizes[3] / 2;
    const int* row = ei;
    const int* col = ei + E;

    // uniform per-(block,partition) capacity: mean + 8 sigma + 64, %8==0
    int npart = (N > 0) ? (N + PART_SIZE - 1) / PART_SIZE : 1;
    double mb = (N > 0) ? (double)E * PART_SIZE / N / PACK_BLOCKS : 0.0;
    int cap = ((int)(mb + 8.0 * sqrt(mb + 1.0) + 64.0) + 7) & ~7;
    size_t bucketShorts = (size_t)npart * PACK_BLOCKS * (size_t)cap;
    int nblkCount = npart * BPP;

    // LDS stage-capacity guard: per round a block stages ~8192 edges; the
    // hottest partition must fit in STAGE_TOTAL/npart with 8-sigma margin.
    // Production N=200000: need 671+207+32=910 <= 1024. OK.
    int stageCap = STAGE_TOTAL / npart;
    double mbR = 8192.0 * ((N >= PART_SIZE) ? ((double)PART_SIZE / (double)N) : 1.0);
    bool stageOk = (N > 0) && (mbR + 8.0 * sqrt(mbR + 1.0) + 32.0) <= (double)stageCap;

    // ws layout: [partials 4K][hist 512K][ovfCnt 256B][gSegCnt]
    //            [p_m][ovf 256K][bm 26.6K][buckets u16][scratch]
    char* ws = (char*)d_ws;
    double* partials = (double*)ws;
    size_t histOff = 4096;
    int* hist = (int*)(ws + histOff);
    size_t ovfCntOff = histOff + (size_t)HIST_BINS * sizeof(int);
    unsigned int* ovfCnt = (unsigned int*)(ws + ovfCntOff);
    size_t gSegOff = ovfCntOff + 256;
    int* gSegCnt = (int*)(ws + gSegOff);
    size_t pmOff = gSegOff + (((size_t)PACK_BLOCKS * NPART_MAX * sizeof(int) + 255) & ~(size_t)255);
    unsigned int* p_m = (unsigned int*)(ws + pmOff);
    size_t pmBytes = ((size_t)N * 4 + 255) & ~(size_t)255;
    size_t ovfOff = pmOff + pmBytes;
    unsigned int* ovf = (unsigned int*)(ws + ovfOff);
    size_t bmOff = ovfOff + (size_t)OVF_CAP * 4;
    unsigned int* bm = (unsigned int*)(ws + bmOff);
    size_t bucketsOff = bmOff + (size_t)BM_WORDS_MAX * 4;
    unsigned short* buckets = (unsigned short*)(ws + bucketsOff);
    size_t scratchOff = bucketsOff + ((bucketShorts * 2 + 255) & ~(size_t)255);
    unsigned int* scratch = (unsigned int*)(ws + scratchOff);
    size_t totalFast = scratchOff + (size_t)nblkCount * PART_WORDS * 4;

    bool fast = (ws_size >= totalFast) && (N <= MAXN) && (N > 0) && stageOk;
    const int threads = 256;
    int nblocks = (N + threads - 1) / threads;
    int bmWords = (N + 31) / 32;

    if (fast) {
        // zero hist + ovfCnt (contiguous); everything else is fully written
        (void)hipMemsetAsync(ws + histOff, 0, (size_t)HIST_BINS * sizeof(int) + 256, stream);
        bitmask_kernel<<<nblocks, threads, 0, stream>>>(x, bm, N);
        pack_bucket_kernel<<<PACK_BLOCKS, PACK_THREADS, 0, stream>>>(
            row, col, bm, buckets, gSegCnt, ovf, ovfCnt, cap, npart, bmWords, E);
        count_bucket_kernel<<<nblkCount, COUNT_THREADS, 0, stream>>>(
            buckets, gSegCnt, ovf, ovfCnt, cap, scratch);
        int mwords = npart * PART_WORDS;
        int mblocks = (mwords + threads - 1) / threads;
        merge_hist_kernel<<<mblocks, threads, 0, stream>>>(scratch, x, p_m, hist, N, npart);
    } else {
        (void)hipMemsetAsync(d_ws, 0, pmOff + pmBytes, stream);
        int E4 = E >> 2;
        int eblocks = (E4 + threads - 1) / threads;
        if (eblocks < 1) eblocks = 1;
        edge_atomic_kernel<<<eblocks, threads, 0, stream>>>(row, col, x, p_m, E);
        hist_from_pm_kernel<<<nblocks, threads, 0, stream>>>(x, p_m, hist, N);
    }
    loss_kernel<<<LOSS_BLOCKS, threads, 0, stream>>>(outp, x, y, p_m, hist, partials, N);
    final_kernel<<<1, threads, 0, stream>>>(partials, (float*)d_out, LOSS_BLOCKS);
}

// Round 5
// 225.425 us; speedup vs baseline: 3.0413x; 1.0151x over previous
//
#include <hip/hip_runtime.h>
#include <math.h>

// weighted_loss: graph-weighted cross entropy.
//   deg/s0 per node (s1 = deg - s0), cnt = #nodes sharing key (x, s0, s1),
//   w = cnt^-0.5, out = sum(w*nll)/sum(w).
//
// Hard-won gfx950 facts driving this design:
//  R1-4: global atomics execute at the memory-side coherence point, ~26 G/s
//        distributed, 32 B write-through each, SCOPE-INDEPENDENT.
//  R7:   same-address global atomics serialize at ~12.5 ns/op.
//  R5-9: LDS-privatized counting + bucketed single-read pass: 740->256 us.
//  R10:  u16 bucket entries (local:15|xbit:1) halved pack writes/count reads.
//  R11:  49 parts regressed pack (store scatter worse).
//  R12:  NT stores: WRITE 25.7->74.7 MB, perf UNCHANGED -> pack is line-
//        TRANSACTION bound, not byte bound; FETCH 50MB = edge stream.
//  R13:  stage guard bug sent production to fallback (685us).
//  R14:  LDS write-combined pack CONFIRMED: 267->228.8us => pack ~25us
//        (was 63), near its 102MB-load floor. Remaining: fill 60 +
//        ~75-100us fixed harness overhead + ~65us of kernels (floor ~45).
//  R15 (this round): consolidation.
//        - hist/ovfCnt zeroing folded into bitmask (drop memset dispatch).
//        - count: dual-segment interleave per wave -> 2x outstanding loads
//          (count is latency-exposed at ~1.6 blocks/CU).

#define KDIM 256
#define HIST_BINS (2 * KDIM * KDIM)
#define PART_BITS 14
#define PART_SIZE (1 << PART_BITS)       // 16384 nodes per partition
#define PART_WORDS (PART_SIZE / 2)       // 8192 u32, 2 nodes/word (s0:8|deg:8)
#define NPART_MAX 13
#define MAXN (NPART_MAX * PART_SIZE)     // 212992
#define BM_WORDS_MAX (MAXN / 32)         // 6656 u32 = 26.6 KB
#define PACK_BLOCKS 512
#define PACK_THREADS 1024
#define STAGE_TOTAL (NPART_MAX * 1024)   // 13312 u16 entries = 26.6 KB
#define BPP 32                           // count replica blocks per partition
#define CSLICES (PACK_BLOCKS / BPP)      // 16 pack-segments per count block
#define COUNT_THREADS 512
#define COUNT_WAVES (COUNT_THREADS / 64) // 8; CSLICES == 2*COUNT_WAVES
#define LOSS_BLOCKS 256
#define OVF_CAP 65536
#define ZERO_WORDS (HIST_BINS + 64)      // hist + ovfCnt block (contiguous)

static_assert(CSLICES == 2 * COUNT_WAVES, "count dual-segment layout");

typedef int iv4 __attribute__((ext_vector_type(4)));
typedef unsigned int uv4 __attribute__((ext_vector_type(4)));

// ------------- kernel A0: x -> bitmask (ballot) + zero hist/ovfCnt -------------
__global__ __launch_bounds__(256) void bitmask_kernel(
    const int* __restrict__ x, unsigned int* __restrict__ bm,
    unsigned int* __restrict__ zeroReg, int N)
{
    int i = blockIdx.x * blockDim.x + threadIdx.x;
    unsigned long long m = __ballot(i < N && x[i] > 0);
    if ((i & 31) == 0 && i < N)
        bm[i >> 5] = (unsigned int)((i & 32) ? (m >> 32) : m);
    for (int w = i; w < ZERO_WORDS; w += gridDim.x * blockDim.x)
        zeroReg[w] = 0u;
}

// ---------------- kernel A: bucketing pack (LDS write-combined) ----------------
__global__ __launch_bounds__(PACK_THREADS, 8) void pack_bucket_kernel(
    const int* __restrict__ row, const int* __restrict__ col,
    const unsigned int* __restrict__ bm,
    unsigned short* __restrict__ buckets,
    int* __restrict__ gSegCnt,           // [PACK_BLOCKS][NPART_MAX]
    unsigned int* __restrict__ ovf, unsigned int* __restrict__ ovfCnt,
    int cap, int npart, int bmWords, int E)
{
    __shared__ unsigned int bmLds[BM_WORDS_MAX];        // 26.6 KB
    __shared__ unsigned short stage[STAGE_TOTAL];       // 26.6 KB
    __shared__ int stageCnt[NPART_MAX];
    __shared__ int offLds[NPART_MAX];
    for (int w = threadIdx.x; w < bmWords; w += blockDim.x) bmLds[w] = bm[w];
    if (threadIdx.x < NPART_MAX) { stageCnt[threadIdx.x] = 0; offLds[threadIdx.x] = 0; }
    __syncthreads();

    int tid = blockIdx.x * blockDim.x + threadIdx.x;
    int stride = gridDim.x * blockDim.x;
    int E4 = E >> 2;
    const iv4* row4 = (const iv4*)row;
    const iv4* col4 = (const iv4*)col;
    int stageCap = STAGE_TOTAL / npart;
    int wave = threadIdx.x >> 6;
    int lane = threadIdx.x & 63;
    int nwaves = blockDim.x >> 6;
    int nrounds = (E4 + 2 * stride - 1) / (2 * stride);
    if (nrounds < 1) nrounds = 1;

#define XBIT(c) ((bmLds[((unsigned)(c)) >> 5] >> ((c) & 31)) & 1u)
#define PUT(nd, cl)                                                             \
    {                                                                           \
        unsigned int node = (unsigned int)(nd);                                 \
        unsigned int xb = XBIT(cl);                                             \
        int b = (int)(node >> PART_BITS);                                       \
        unsigned int entry = ((node & (PART_SIZE - 1u)) << 1) | xb;             \
        int slot = atomicAdd(&stageCnt[b], 1);                                  \
        if (slot < stageCap)                                                    \
            stage[b * stageCap + slot] = (unsigned short)entry;                 \
        else {                                                                  \
            unsigned int os = atomicAdd(ovfCnt, 1u);                            \
            if (os < OVF_CAP) ovf[os] = (node << 1) | xb;                       \
        }                                                                       \
    }

    for (int r = 0; r < nrounds; ++r) {
        int i = tid + r * 2 * stride;
        if (i + stride < E4) {
            iv4 r0 = __builtin_nontemporal_load(&row4[i]);
            iv4 c0 = __builtin_nontemporal_load(&col4[i]);
            iv4 r1 = __builtin_nontemporal_load(&row4[i + stride]);
            iv4 c1 = __builtin_nontemporal_load(&col4[i + stride]);
            PUT(r0.x, c0.x) PUT(r0.y, c0.y) PUT(r0.z, c0.z) PUT(r0.w, c0.w)
            PUT(r1.x, c1.x) PUT(r1.y, c1.y) PUT(r1.z, c1.z) PUT(r1.w, c1.w)
        } else if (i < E4) {
            iv4 r0 = __builtin_nontemporal_load(&row4[i]);
            iv4 c0 = __builtin_nontemporal_load(&col4[i]);
            PUT(r0.x, c0.x) PUT(r0.y, c0.y) PUT(r0.z, c0.z) PUT(r0.w, c0.w)
        }
        if (r == nrounds - 1) {
            for (int e = (E4 << 2) + tid; e < E; e += stride)
                PUT(row[e], col[e])
        }
        __syncthreads();
        // flush: one wave per partition, consecutive (coalesced) stores
        for (int b = wave; b < npart; b += nwaves) {
            int cnt = stageCnt[b];
            if (cnt > stageCap) cnt = stageCap;
            int off = offLds[b];
            int avail = cap - off;
            if (avail < 0) avail = 0;
            int wr = cnt < avail ? cnt : avail;
            unsigned short* dst =
                buckets + (size_t)(b * PACK_BLOCKS + (int)blockIdx.x) * (size_t)cap + off;
            const unsigned short* src = stage + b * stageCap;
            for (int k = lane; k < wr; k += 64) dst[k] = src[k];
            for (int k = wr + lane; k < cnt; k += 64) {   // beyond cap: spill
                unsigned int en = src[k];
                unsigned int node = ((unsigned int)b << PART_BITS) | (en >> 1);
                unsigned int os = atomicAdd(ovfCnt, 1u);
                if (os < OVF_CAP) ovf[os] = (node << 1) | (en & 1u);
            }
            if (lane == 0) { offLds[b] = off + wr; stageCnt[b] = 0; }
        }
        __syncthreads();
    }
#undef PUT
#undef XBIT

    if (threadIdx.x < npart)
        gSegCnt[blockIdx.x * NPART_MAX + threadIdx.x] = offLds[threadIdx.x];
}

// ---------------- kernel B: single-read LDS-privatized count ----------------
// One block = (partition p, replica grp). Each wave owns TWO pack-segments,
// processed interleaved -> 2x outstanding global loads (latency hiding at
// ~1.6 blocks/CU).
__global__ __launch_bounds__(COUNT_THREADS, 8) void count_bucket_kernel(
    const unsigned short* __restrict__ buckets, const int* __restrict__ gSegCnt,
    const unsigned int* __restrict__ ovf, const unsigned int* __restrict__ ovfCnt,
    int cap, unsigned int* __restrict__ scratch)
{
    __shared__ unsigned int lds[PART_WORDS];   // 32 KB
    int p = blockIdx.x / BPP;
    int grp = blockIdx.x % BPP;
    for (int w = threadIdx.x; w < PART_WORDS; w += blockDim.x) lds[w] = 0;
    __syncthreads();

#define DO1(e)                                                                  \
    {                                                                           \
        unsigned int j = (e) >> 1;  /* partition-local: always < PART_SIZE */   \
        unsigned int val = (((e) & 1u) ? 0x0101u : 0x0001u) << ((j & 1u) << 4); \
        atomicAdd(&lds[j >> 1], val);                                           \
    }
#define DOW(w) { DO1((w) & 0xFFFFu) DO1((w) >> 16) }
    int sl0 = grp * CSLICES;
    int wave = threadIdx.x >> 6;
    int lane = threadIdx.x & 63;
    int pbA = sl0 + wave;
    int pbB = sl0 + wave + COUNT_WAVES;
    int cntA = gSegCnt[pbA * NPART_MAX + p];
    int cntB = gSegCnt[pbB * NPART_MAX + p];
    const unsigned short* baseA =
        buckets + (size_t)(p * PACK_BLOCKS + pbA) * (size_t)cap;
    const unsigned short* baseB =
        buckets + (size_t)(p * PACK_BLOCKS + pbB) * (size_t)cap;
    const uv4* a8 = (const uv4*)baseA;   // cap %8==0 -> 16B-aligned
    const uv4* b8 = (const uv4*)baseB;
    int na = cntA >> 3, nb = cntB >> 3;
    int mx = na > nb ? na : nb;
    for (int i = lane; i < mx; i += 64) {
        bool ha = i < na, hb = i < nb;
        uv4 va, vb;
        if (ha) va = a8[i];
        if (hb) vb = b8[i];              // both loads in flight before use
        if (ha) { DOW(va.x) DOW(va.y) DOW(va.z) DOW(va.w) }
        if (hb) { DOW(vb.x) DOW(vb.y) DOW(vb.z) DOW(vb.w) }
    }
    for (int k = (na << 3) + lane; k < cntA; k += 64)
        DO1((unsigned int)baseA[k]);
    for (int k = (nb << 3) + lane; k < cntB; k += 64)
        DO1((unsigned int)baseB[k]);
    // overflow region (normally empty): full node<<1|xbit u32 entries,
    // filtered by partition; grp 0 only (others would double-count).
    if (grp == 0) {
        unsigned int oc = *ovfCnt;
        if (oc > OVF_CAP) oc = OVF_CAP;
        unsigned int pbase = (unsigned int)p << PART_BITS;
        for (unsigned int i = threadIdx.x; i < oc; i += blockDim.x) {
            unsigned int e = ovf[i];
            unsigned int j = (e >> 1) - pbase;
            if (j < PART_SIZE) {
                unsigned int val = ((e & 1u) ? 0x0101u : 0x0001u) << ((j & 1u) << 4);
                atomicAdd(&lds[j >> 1], val);
            }
        }
    }
#undef DOW
#undef DO1
    __syncthreads();
    unsigned int* dst = scratch + (size_t)blockIdx.x * PART_WORDS;
    for (int w = threadIdx.x; w < PART_WORDS; w += blockDim.x)
        dst[w] = lds[w];
}

// ---------------- kernel C: merge replicas + key histogram ----------------
__global__ __launch_bounds__(256) void merge_hist_kernel(
    const unsigned int* __restrict__ scratch, const int* __restrict__ x,
    unsigned int* __restrict__ p_m, int* __restrict__ hist, int N, int npart)
{
    int gw = blockIdx.x * blockDim.x + threadIdx.x;
    if (gw >= npart * PART_WORDS) return;
    int part = gw >> (PART_BITS - 1);
    int lw = gw & (PART_WORDS - 1);
    const unsigned int* base = scratch + ((size_t)part * BPP) * PART_WORDS + lw;
    unsigned int s = 0;
#pragma unroll 8
    for (int c = 0; c < BPP; ++c) s += base[(size_t)c * PART_WORDS];
    // byte fields sum without carry: true deg <= ~110 < 256
    int node0 = (part << PART_BITS) | (lw << 1);
    if (node0 < N) {
        unsigned int deg = s & 0xFFu, s0 = (s >> 8) & 0xFFu;
        p_m[node0] = deg | (s0 << 16);
        int key = ((x[node0] > 0) ? KDIM * KDIM : 0) + (int)(s0 * KDIM + (deg - s0));
        atomicAdd(&hist[key], 1);
    }
    int node1 = node0 + 1;
    if (node1 < N) {
        unsigned int deg = (s >> 16) & 0xFFu, s0 = (s >> 24) & 0xFFu;
        p_m[node1] = deg | (s0 << 16);
        int key = ((x[node1] > 0) ? KDIM * KDIM : 0) + (int)(s0 * KDIM + (deg - s0));
        atomicAdd(&hist[key], 1);
    }
}

// ---------------- fallback path (ws too small / N too big) ----------------
__global__ __launch_bounds__(256) void edge_atomic_kernel(
    const int* __restrict__ row, const int* __restrict__ col,
    const int* __restrict__ x, unsigned int* __restrict__ p_m, int E)
{
    int tid = blockIdx.x * blockDim.x + threadIdx.x;
    int stride = gridDim.x * blockDim.x;
    int E4 = E >> 2;
    const iv4* row4 = (const iv4*)row;
    const iv4* col4 = (const iv4*)col;
    for (int i = tid; i < E4; i += stride) {
        iv4 r = row4[i];
        iv4 c = col4[i];
        atomicAdd(&p_m[r.x], (x[c.x] > 0) ? 0x10001u : 1u);
        atomicAdd(&p_m[r.y], (x[c.y] > 0) ? 0x10001u : 1u);
        atomicAdd(&p_m[r.z], (x[c.z] > 0) ? 0x10001u : 1u);
        atomicAdd(&p_m[r.w], (x[c.w] > 0) ? 0x10001u : 1u);
    }
    for (int e = (E4 << 2) + tid; e < E; e += stride)
        atomicAdd(&p_m[row[e]], (x[col[e]] > 0) ? 0x10001u : 1u);
}

__global__ void hist_from_pm_kernel(const int* __restrict__ x,
                                    const unsigned int* __restrict__ p_m,
                                    int* __restrict__ hist, int N)
{
    int i = blockIdx.x * blockDim.x + threadIdx.x;
    if (i >= N) return;
    unsigned int pi = p_m[i];
    int deg = (int)(pi & 0xFFFFu);
    int s0 = (int)(pi >> 16);
    int s1 = deg - s0;
    s0 = min(s0, KDIM - 1);
    s1 = min(s1, KDIM - 1);
    int key = ((x[i] > 0) ? KDIM * KDIM : 0) + s0 * KDIM + s1;
    atomicAdd(&hist[key], 1);
}

// ---------------- kernel D: weighted NLL -> per-block partials ----------------
__global__ __launch_bounds__(256) void loss_kernel(
    const float* __restrict__ outp, const int* __restrict__ x,
    const int* __restrict__ y, const unsigned int* __restrict__ p_m,
    const int* __restrict__ hist, double* __restrict__ partials, int N)
{
    __shared__ double red[8];
    int tid = blockIdx.x * blockDim.x + threadIdx.x;
    int stride = gridDim.x * blockDim.x;
    double wn = 0.0, wsum = 0.0;
    const float2* out2 = (const float2*)outp;
    for (int i = tid; i < N; i += stride) {
        unsigned int pi = p_m[i];
        int deg = (int)(pi & 0xFFFFu);
        int s0 = (int)(pi >> 16);
        int s1 = deg - s0;
        s0 = min(s0, KDIM - 1);
        s1 = min(s1, KDIM - 1);
        int key = ((x[i] > 0) ? KDIM * KDIM : 0) + s0 * KDIM + s1;
        int cnt = hist[key];
        float w = 1.0f / sqrtf((float)cnt);
        float2 o = out2[i];
        float m = fmaxf(o.x, o.y);
        float lse = m + logf(expf(o.x - m) + expf(o.y - m));
        float oy = (y[i] == 0) ? o.x : o.y;
        wn += (double)(w * (lse - oy));
        wsum += (double)w;
    }
    for (int off = 32; off > 0; off >>= 1) {
        wn += __shfl_down(wn, off);
        wsum += __shfl_down(wsum, off);
    }
    int wave = threadIdx.x >> 6;
    if ((threadIdx.x & 63) == 0) { red[wave * 2] = wn; red[wave * 2 + 1] = wsum; }
    __syncthreads();
    if (threadIdx.x == 0) {
        double twn = 0.0, tws = 0.0;
        for (int wv = 0; wv < (int)(blockDim.x >> 6); ++wv) {
            twn += red[wv * 2]; tws += red[wv * 2 + 1];
        }
        partials[blockIdx.x * 2] = twn;
        partials[blockIdx.x * 2 + 1] = tws;
    }
}

__global__ __launch_bounds__(256) void final_kernel(
    const double* __restrict__ partials, float* __restrict__ out, int nPart)
{
    __shared__ double red[8];
    double wn = 0.0, wsum = 0.0;
    for (int i = threadIdx.x; i < nPart; i += blockDim.x) {
        wn += partials[i * 2];
        wsum += partials[i * 2 + 1];
    }
    for (int off = 32; off > 0; off >>= 1) {
        wn += __shfl_down(wn, off);
        wsum += __shfl_down(wsum, off);
    }
    int wave = threadIdx.x >> 6;
    if ((threadIdx.x & 63) == 0) { red[wave * 2] = wn; red[wave * 2 + 1] = wsum; }
    __syncthreads();
    if (threadIdx.x == 0) {
        double twn = 0.0, tws = 0.0;
        for (int wv = 0; wv < (int)(blockDim.x >> 6); ++wv) {
            twn += red[wv * 2]; tws += red[wv * 2 + 1];
        }
        out[0] = (float)(twn / tws);
    }
}

extern "C" void kernel_launch(void* const* d_in, const int* in_sizes, int n_in,
                              void* d_out, int out_size, void* d_ws, size_t ws_size,
                              hipStream_t stream) {
    const float* outp = (const float*)d_in[0];   // (N,2) fp32
    const int*   x    = (const int*)d_in[1];     // (N,)
    const int*   y    = (const int*)d_in[2];     // (N,)
    const int*   ei   = (const int*)d_in[3];     // (2,E)
    int N = in_sizes[1];
    int E = in_sizes[3] / 2;
    const int* row = ei;
    const int* col = ei + E;

    // uniform per-(block,partition) capacity: mean + 8 sigma + 64, %8==0
    int npart = (N > 0) ? (N + PART_SIZE - 1) / PART_SIZE : 1;
    double mb = (N > 0) ? (double)E * PART_SIZE / N / PACK_BLOCKS : 0.0;
    int cap = ((int)(mb + 8.0 * sqrt(mb + 1.0) + 64.0) + 7) & ~7;
    size_t bucketShorts = (size_t)npart * PACK_BLOCKS * (size_t)cap;
    int nblkCount = npart * BPP;

    // LDS stage-capacity guard: per round a block stages ~8192 edges; the
    // hottest partition must fit in STAGE_TOTAL/npart with 8-sigma margin.
    // Production N=200000: need 671+207+32=910 <= 1024. OK.
    int stageCap = STAGE_TOTAL / npart;
    double mbR = 8192.0 * ((N >= PART_SIZE) ? ((double)PART_SIZE / (double)N) : 1.0);
    bool stageOk = (N > 0) && (mbR + 8.0 * sqrt(mbR + 1.0) + 32.0) <= (double)stageCap;

    // ws layout: [partials 4K][hist 512K][ovfCnt 256B][gSegCnt]
    //            [p_m][ovf 256K][bm 26.6K][buckets u16][scratch]
    char* ws = (char*)d_ws;
    double* partials = (double*)ws;
    size_t histOff = 4096;
    int* hist = (int*)(ws + histOff);
    size_t ovfCntOff = histOff + (size_t)HIST_BINS * sizeof(int);
    unsigned int* ovfCnt = (unsigned int*)(ws + ovfCntOff);
    size_t gSegOff = ovfCntOff + 256;
    int* gSegCnt = (int*)(ws + gSegOff);
    size_t pmOff = gSegOff + (((size_t)PACK_BLOCKS * NPART_MAX * sizeof(int) + 255) & ~(size_t)255);
    unsigned int* p_m = (unsigned int*)(ws + pmOff);
    size_t pmBytes = ((size_t)N * 4 + 255) & ~(size_t)255;
    size_t ovfOff = pmOff + pmBytes;
    unsigned int* ovf = (unsigned int*)(ws + ovfOff);
    size_t bmOff = ovfOff + (size_t)OVF_CAP * 4;
    unsigned int* bm = (unsigned int*)(ws + bmOff);
    size_t bucketsOff = bmOff + (size_t)BM_WORDS_MAX * 4;
    unsigned short* buckets = (unsigned short*)(ws + bucketsOff);
    size_t scratchOff = bucketsOff + ((bucketShorts * 2 + 255) & ~(size_t)255);
    unsigned int* scratch = (unsigned int*)(ws + scratchOff);
    size_t totalFast = scratchOff + (size_t)nblkCount * PART_WORDS * 4;

    bool fast = (ws_size >= totalFast) && (N <= MAXN) && (N > 0) && stageOk;
    const int threads = 256;
    int nblocks = (N + threads - 1) / threads;
    int bmWords = (N + 31) / 32;

    if (fast) {
        // hist + ovfCnt zeroing folded into bitmask_kernel (contiguous region)
        bitmask_kernel<<<nblocks, threads, 0, stream>>>(
            x, bm, (unsigned int*)(ws + histOff), N);
        pack_bucket_kernel<<<PACK_BLOCKS, PACK_THREADS, 0, stream>>>(
            row, col, bm, buckets, gSegCnt, ovf, ovfCnt, cap, npart, bmWords, E);
        count_bucket_kernel<<<nblkCount, COUNT_THREADS, 0, stream>>>(
            buckets, gSegCnt, ovf, ovfCnt, cap, scratch);
        int mwords = npart * PART_WORDS;
        int mblocks = (mwords + threads - 1) / threads;
        merge_hist_kernel<<<mblocks, threads, 0, stream>>>(scratch, x, p_m, hist, N, npart);
    } else {
        (void)hipMemsetAsync(d_ws, 0, pmOff + pmBytes, stream);
        int E4 = E >> 2;
        int eblocks = (E4 + threads - 1) / threads;
        if (eblocks < 1) eblocks = 1;
        edge_atomic_kernel<<<eblocks, threads, 0, stream>>>(row, col, x, p_m, E);
        hist_from_pm_kernel<<<nblocks, threads, 0, stream>>>(x, p_m, hist, N);
    }
    loss_kernel<<<LOSS_BLOCKS, threads, 0, stream>>>(outp, x, y, p_m, hist, partials, N);
    final_kernel<<<1, threads, 0, stream>>>(partials, (float*)d_out, LOSS_BLOCKS);
}